// Round 1
// baseline (234.270 us; speedup 1.0000x reference)
//
#include <hip/hip_runtime.h>
#include <math.h>

#define D_MELS 80
#define T_DIM  4000
#define NQ     10   // number of scalar accumulators

// ws layout: [0]=l1_sum [1]=band_sum [2]=diff2_sum [3]=tgt2_sum [4]=energy_sum
//            [5]=mask_sum [6]=delta_sum [7]=dmask_sum [8]=delta2_sum [9]=d2mask_sum

__global__ __launch_bounds__(256) void mel_loss_main(
    const float* __restrict__ pred, const float* __restrict__ tgt,
    const float* __restrict__ mask, const float* __restrict__ w,
    float* __restrict__ ws, int BT)
{
    int r = blockIdx.x * blockDim.x + threadIdx.x;

    float v_l1 = 0.f, v_band = 0.f, v_diff2 = 0.f, v_tgt2 = 0.f, v_energy = 0.f;
    float v_m = 0.f, v_d = 0.f, v_dm = 0.f, v_d2 = 0.f, v_d2m = 0.f;

    if (r < BT) {
        int t = r % T_DIM;
        bool has1 = (t >= 1);
        bool has2 = (t >= 2);

        const float* p0 = pred + (size_t)r * D_MELS;
        const float* q0 = tgt  + (size_t)r * D_MELS;
        // clamp halo pointers to a valid row when absent; contributions are
        // zeroed by the mask products below (mt1/mt2 forced to 0)
        const float* p1 = has1 ? p0 - D_MELS     : p0;
        const float* q1 = has1 ? q0 - D_MELS     : q0;
        const float* p2 = has2 ? p0 - 2 * D_MELS : p0;
        const float* q2 = has2 ? q0 - 2 * D_MELS : q0;

        float mt  = mask[r];
        float mt1 = has1 ? mask[r - 1] : 0.f;
        float mt2 = has2 ? mask[r - 2] : 0.f;

        float l1r = 0.f, bandr = 0.f, sqr = 0.f, t2r = 0.f, er = 0.f;
        float dr = 0.f, d2r = 0.f;

        #pragma unroll
        for (int j = 0; j < D_MELS / 4; ++j) {
            float4 p  = ((const float4*)p0)[j];
            float4 q  = ((const float4*)q0)[j];
            float4 pa = ((const float4*)p1)[j];
            float4 qa = ((const float4*)q1)[j];
            float4 pb = ((const float4*)p2)[j];
            float4 qb = ((const float4*)q2)[j];
            float4 wv = ((const float4*)w)[j];

            float e0 = p.x - q.x, e1 = p.y - q.y, e2 = p.z - q.z, e3 = p.w - q.w;
            float f0 = pa.x - qa.x, f1 = pa.y - qa.y, f2 = pa.z - qa.z, f3 = pa.w - qa.w;
            float g0 = pb.x - qb.x, g1 = pb.y - qb.y, g2 = pb.z - qb.z, g3 = pb.w - qb.w;

            float a0 = fabsf(e0), a1 = fabsf(e1), a2 = fabsf(e2), a3 = fabsf(e3);
            l1r   += a0 + a1 + a2 + a3;
            bandr += a0 * wv.x + a1 * wv.y + a2 * wv.z + a3 * wv.w;
            sqr   += e0 * e0 + e1 * e1 + e2 * e2 + e3 * e3;
            t2r   += q.x * q.x + q.y * q.y + q.z * q.z + q.w * q.w;
            er    += e0 + e1 + e2 + e3;
            // first temporal difference of e (pairs (t-1, t))
            dr  += fabsf(e0 - f0) + fabsf(e1 - f1) + fabsf(e2 - f2) + fabsf(e3 - f3);
            // second temporal difference of e (triples (t-2, t-1, t))
            d2r += fabsf(e0 - 2.f * f0 + g0) + fabsf(e1 - 2.f * f1 + g1)
                 + fabsf(e2 - 2.f * f2 + g2) + fabsf(e3 - 2.f * f3 + g3);
        }

        float dmv  = mt * mt1;        // zero when t==0
        float d2mv = mt * mt1 * mt2;  // zero when t<2

        v_l1     = l1r * mt;
        v_band   = bandr * mt;
        v_diff2  = sqr * mt;
        v_tgt2   = t2r * mt;
        v_energy = fabsf(er) * mt;    // divide by D once in finalize
        v_m      = mt;
        v_d      = dr * dmv;
        v_dm     = dmv;
        v_d2     = d2r * d2mv;
        v_d2m    = d2mv;
    }

    // ---- block reduction: wave shuffle then LDS then atomics ----
    float vals[NQ] = {v_l1, v_band, v_diff2, v_tgt2, v_energy,
                      v_m, v_d, v_dm, v_d2, v_d2m};
    #pragma unroll
    for (int q = 0; q < NQ; ++q) {
        float v = vals[q];
        #pragma unroll
        for (int off = 32; off > 0; off >>= 1)
            v += __shfl_down(v, off, 64);
        vals[q] = v;
    }

    __shared__ float red[4][NQ];
    int wave = threadIdx.x >> 6;
    int lane = threadIdx.x & 63;
    if (lane == 0) {
        #pragma unroll
        for (int q = 0; q < NQ; ++q) red[wave][q] = vals[q];
    }
    __syncthreads();
    if (threadIdx.x < NQ) {
        float s = red[0][threadIdx.x] + red[1][threadIdx.x]
                + red[2][threadIdx.x] + red[3][threadIdx.x];
        atomicAdd(&ws[threadIdx.x], s);
    }
}

__global__ void mel_loss_finalize(const float* __restrict__ ws,
                                  const float* __restrict__ w,
                                  float* __restrict__ out)
{
    if (blockIdx.x == 0 && threadIdx.x == 0) {
        float l1s = ws[0], bands = ws[1], diff2 = ws[2], tgt2 = ws[3];
        float energys = ws[4], ms = ws[5], ds = ws[6], dms = ws[7];
        float d2s = ws[8], d2ms = ws[9];

        float wsum = 0.f;
        for (int d = 0; d < D_MELS; ++d) wsum += w[d];
        float wmean = wsum / (float)D_MELS;

        float n1  = fmaxf(ms  * (float)D_MELS, 1.f);
        float nd  = fmaxf(dms * (float)D_MELS, 1.f);
        float nd2 = fmaxf(d2ms * (float)D_MELS, 1.f);

        float l1_loss     = l1s / n1;
        float delta_loss  = ds / nd;
        float delta2_loss = d2s / nd2;
        float sc_num = sqrtf(diff2 / n1);
        float sc_den = fmaxf(sqrtf(tgt2 / n1), 1e-8f);
        float sc_loss = sc_num / sc_den;
        float band_loss = (bands / n1) / wmean;
        float energy_loss = (energys / (float)D_MELS) / fmaxf(ms, 1.f);

        out[0] = 1.0f * l1_loss + 0.5f * delta_loss + 0.25f * delta2_loss
               + 0.5f * sc_loss + 1.0f * band_loss + 0.5f * energy_loss;
    }
}

extern "C" void kernel_launch(void* const* d_in, const int* in_sizes, int n_in,
                              void* d_out, int out_size, void* d_ws, size_t ws_size,
                              hipStream_t stream) {
    const float* pred = (const float*)d_in[0];
    const float* tgt  = (const float*)d_in[1];
    const float* mask = (const float*)d_in[2];
    const float* w    = (const float*)d_in[3];
    int BT = in_sizes[2];                 // B*T = 256000
    float* ws = (float*)d_ws;

    hipMemsetAsync(ws, 0, NQ * sizeof(float), stream);

    int block = 256;
    int grid = (BT + block - 1) / block;
    mel_loss_main<<<grid, block, 0, stream>>>(pred, tgt, mask, w, ws, BT);
    mel_loss_finalize<<<1, 64, 0, stream>>>(ws, w, (float*)d_out);
}

// Round 2
// 198.928 us; speedup vs baseline: 1.1777x; 1.1777x over previous
//
#include <hip/hip_runtime.h>
#include <math.h>

#define D_MELS 80
#define T_DIM  4000
#define NQ     10      // number of scalar accumulators
#define RPB    16      // rows per block-iteration
#define NTHR   (RPB * 20)   // 320 threads = 5 waves; 20 float4 per row
#define NWAVES (NTHR / 64)
#define NBLK   800

// ws layout: [0]=l1_sum [1]=band_sum [2]=diff2_sum [3]=tgt2_sum [4]=energy_sum
//            [5]=mask_sum [6]=delta_sum [7]=dmask_sum [8]=delta2_sum [9]=d2mask_sum

__global__ __launch_bounds__(NTHR) void mel_loss_main(
    const float* __restrict__ pred, const float* __restrict__ tgt,
    const float* __restrict__ mask, const float* __restrict__ w,
    float* __restrict__ ws, int BT)
{
    const int tid = threadIdx.x;
    const int g   = tid % 20;        // float4 group within row
    const int rl  = tid / 20;        // row within block tile

    const float4* p4 = (const float4*)pred;
    const float4* q4 = (const float4*)tgt;
    const float4  wv = ((const float4*)w)[g];

    float v_l1 = 0.f, v_band = 0.f, v_diff2 = 0.f, v_tgt2 = 0.f, v_energy = 0.f;
    float v_m = 0.f, v_d = 0.f, v_dm = 0.f, v_d2 = 0.f, v_d2m = 0.f;

    __shared__ float esum[NTHR];
    __shared__ float red[NWAVES][NQ];

    for (int base = blockIdx.x * RPB; base < BT; base += gridDim.x * RPB) {
        int r = base + rl;
        float my_e = 0.f;
        if (r < BT) {
            int t = r % T_DIM;
            bool has1 = (t >= 1);
            bool has2 = (t >= 2);

            int i0 = r * 20 + g;                   // float4 index, contiguous = base*20 + tid
            int i1 = has1 ? i0 - 20 : i0;
            int i2 = has2 ? i0 - 40 : i0;

            float4 p  = p4[i0];
            float4 q  = q4[i0];
            float4 pa = p4[i1];
            float4 qa = q4[i1];
            float4 pb = p4[i2];
            float4 qb = q4[i2];

            float mt  = mask[r];
            float mt1 = has1 ? mask[r - 1] : 0.f;
            float mt2 = has2 ? mask[r - 2] : 0.f;

            float e0 = p.x - q.x, e1 = p.y - q.y, e2 = p.z - q.z, e3 = p.w - q.w;
            float f0 = pa.x - qa.x, f1 = pa.y - qa.y, f2 = pa.z - qa.z, f3 = pa.w - qa.w;
            float g0 = pb.x - qb.x, g1 = pb.y - qb.y, g2 = pb.z - qb.z, g3 = pb.w - qb.w;

            float a0 = fabsf(e0), a1 = fabsf(e1), a2 = fabsf(e2), a3 = fabsf(e3);

            float l1r   = a0 + a1 + a2 + a3;
            float bandr = a0 * wv.x + a1 * wv.y + a2 * wv.z + a3 * wv.w;
            float sqr   = e0 * e0 + e1 * e1 + e2 * e2 + e3 * e3;
            float t2r   = q.x * q.x + q.y * q.y + q.z * q.z + q.w * q.w;
            float dr  = fabsf(e0 - f0) + fabsf(e1 - f1) + fabsf(e2 - f2) + fabsf(e3 - f3);
            float d2r = fabsf(e0 - 2.f * f0 + g0) + fabsf(e1 - 2.f * f1 + g1)
                      + fabsf(e2 - 2.f * f2 + g2) + fabsf(e3 - 2.f * f3 + g3);

            float dmv  = mt * mt1;
            float d2mv = mt * mt1 * mt2;

            v_l1    += l1r * mt;
            v_band  += bandr * mt;
            v_diff2 += sqr * mt;
            v_tgt2  += t2r * mt;
            v_d     += dr * dmv;
            v_d2    += d2r * d2mv;
            if (g == 0) {            // once per row
                v_m   += mt;
                v_dm  += dmv;
                v_d2m += d2mv;
            }
            my_e = e0 + e1 + e2 + e3;
        }
        esum[tid] = my_e;
        __syncthreads();
        if (tid < RPB) {
            int rr = base + tid;
            if (rr < BT) {
                float s = 0.f;
                #pragma unroll
                for (int k = 0; k < 20; ++k) s += esum[tid * 20 + k];
                v_energy += fabsf(s) * mask[rr];
            }
        }
        __syncthreads();
    }

    // ---- block reduction: wave shuffle then LDS then atomics ----
    float vals[NQ] = {v_l1, v_band, v_diff2, v_tgt2, v_energy,
                      v_m, v_d, v_dm, v_d2, v_d2m};
    #pragma unroll
    for (int q = 0; q < NQ; ++q) {
        float v = vals[q];
        #pragma unroll
        for (int off = 32; off > 0; off >>= 1)
            v += __shfl_down(v, off, 64);
        vals[q] = v;
    }

    int wave = tid >> 6;
    int lane = tid & 63;
    if (lane == 0) {
        #pragma unroll
        for (int q = 0; q < NQ; ++q) red[wave][q] = vals[q];
    }
    __syncthreads();
    if (tid < NQ) {
        float s = 0.f;
        #pragma unroll
        for (int wv2 = 0; wv2 < NWAVES; ++wv2) s += red[wv2][tid];
        atomicAdd(&ws[tid], s);
    }
}

__global__ void mel_loss_finalize(const float* __restrict__ ws,
                                  const float* __restrict__ w,
                                  float* __restrict__ out)
{
    if (blockIdx.x == 0 && threadIdx.x == 0) {
        float l1s = ws[0], bands = ws[1], diff2 = ws[2], tgt2 = ws[3];
        float energys = ws[4], ms = ws[5], ds = ws[6], dms = ws[7];
        float d2s = ws[8], d2ms = ws[9];

        float wsum = 0.f;
        for (int d = 0; d < D_MELS; ++d) wsum += w[d];
        float wmean = wsum / (float)D_MELS;

        float n1  = fmaxf(ms  * (float)D_MELS, 1.f);
        float nd  = fmaxf(dms * (float)D_MELS, 1.f);
        float nd2 = fmaxf(d2ms * (float)D_MELS, 1.f);

        float l1_loss     = l1s / n1;
        float delta_loss  = ds / nd;
        float delta2_loss = d2s / nd2;
        float sc_num = sqrtf(diff2 / n1);
        float sc_den = fmaxf(sqrtf(tgt2 / n1), 1e-8f);
        float sc_loss = sc_num / sc_den;
        float band_loss = (bands / n1) / wmean;
        float energy_loss = (energys / (float)D_MELS) / fmaxf(ms, 1.f);

        out[0] = 1.0f * l1_loss + 0.5f * delta_loss + 0.25f * delta2_loss
               + 0.5f * sc_loss + 1.0f * band_loss + 0.5f * energy_loss;
    }
}

extern "C" void kernel_launch(void* const* d_in, const int* in_sizes, int n_in,
                              void* d_out, int out_size, void* d_ws, size_t ws_size,
                              hipStream_t stream) {
    const float* pred = (const float*)d_in[0];
    const float* tgt  = (const float*)d_in[1];
    const float* mask = (const float*)d_in[2];
    const float* w    = (const float*)d_in[3];
    int BT = in_sizes[2];                 // B*T = 256000
    float* ws = (float*)d_ws;

    hipMemsetAsync(ws, 0, NQ * sizeof(float), stream);

    mel_loss_main<<<NBLK, NTHR, 0, stream>>>(pred, tgt, mask, w, ws, BT);
    mel_loss_finalize<<<1, 64, 0, stream>>>(ws, w, (float*)d_out);
}